// Round 23
// baseline (446.514 us; speedup 1.0000x reference)
//
#include <hip/hip_runtime.h>

typedef __attribute__((ext_vector_type(8))) _Float16 half8;
typedef __attribute__((ext_vector_type(4))) _Float16 half4;
typedef __attribute__((ext_vector_type(4))) float f32x4;

#define SEQ 2048
#define DMODEL 1024
#define NHEAD 16
#define HEADD 64
#define NBH 32          // B * NHEAD
#define LUTW 4096

__device__ __forceinline__ void nt_store_f4(float* p, f32x4 v) {
    __builtin_nontemporal_store(v, (f32x4*)p);
}

// async global->LDS, 16B per lane
#define GLOAD16(gp, lp) __builtin_amdgcn_global_load_lds(                    \
    (const __attribute__((address_space(1))) void*)(gp),                     \
    (__attribute__((address_space(3))) void*)(lp), 16, 0, 0)

// raw barrier: orders LDS only; global loads/stores stay in flight across it
#define LDS_BAR() do {                                   \
    __builtin_amdgcn_sched_barrier(0);                   \
    asm volatile("s_waitcnt lgkmcnt(0)" ::: "memory");   \
    __builtin_amdgcn_sched_barrier(0);                   \
    __builtin_amdgcn_s_barrier();                        \
    __builtin_amdgcn_sched_barrier(0);                   \
} while (0)

// ---------------- T5 relative position bucket ----------------
__device__ __forceinline__ int rel_bucket(int rel) {
    int ret = (rel > 0) ? 16 : 0;
    int rp = rel < 0 ? -rel : rel;
    if (rp < 8) return ret + rp;
    float x = logf((float)rp * 0.125f) / 2.7725887f * 8.0f;
    int v = 8 + (int)x;
    v = v < 15 ? v : 15;
    return ret + v;
}

// ---------------- prep: all casts + bias LUT in one launch ----------------
__global__ __launch_bounds__(256) void prep_kernel(const float* __restrict__ hs,
                                                   const float* __restrict__ Wq,
                                                   const float* __restrict__ Wk,
                                                   const float* __restrict__ Wv,
                                                   const float* __restrict__ Wo,
                                                   const float* __restrict__ rel_bias,
                                                   _Float16* __restrict__ Xh,
                                                   _Float16* __restrict__ Wqh,
                                                   _Float16* __restrict__ Wkh,
                                                   _Float16* __restrict__ Wvh,
                                                   _Float16* __restrict__ Woh,
                                                   float* __restrict__ lut) {
    int bid = blockIdx.x;
    if (bid < 4096) {
        const float* in;
        _Float16* out;
        int base;
        if (bid < 2048)      { in = hs; out = Xh;  base = bid; }
        else if (bid < 2560) { in = Wq; out = Wqh; base = bid - 2048; }
        else if (bid < 3072) { in = Wk; out = Wkh; base = bid - 2560; }
        else if (bid < 3584) { in = Wv; out = Wvh; base = bid - 3072; }
        else                 { in = Wo; out = Woh; base = bid - 3584; }
        int i = (base * 256 + threadIdx.x) * 8;
        f32x4 a = *(const f32x4*)(in + i);
        f32x4 b = *(const f32x4*)(in + i + 4);
        half8 r;
        r[0] = (_Float16)a[0]; r[1] = (_Float16)a[1];
        r[2] = (_Float16)a[2]; r[3] = (_Float16)a[3];
        r[4] = (_Float16)b[0]; r[5] = (_Float16)b[1];
        r[6] = (_Float16)b[2]; r[7] = (_Float16)b[3];
        *(half8*)(out + i) = r;
    } else {
        int i = (bid - 4096) * 256 + threadIdx.x;   // 16 * 4096
        int h = i >> 12;
        int idx = i & (LUTW - 1);
        int rel = idx - 2047;
        int b = rel_bucket(rel);
        lut[i] = rel_bias[b * NHEAD + h];
    }
}

// ---------------- m97-style GEMM body: global_load_lds staging, 128x128 tile ----------------
__device__ __forceinline__ void gemm_body_gll(const _Float16* __restrict__ A,
                                              const _Float16* __restrict__ B,
                                              _Float16* As, _Float16* Bs,
                                              int row0, int col0,
                                              f32x4 (&acc)[4][4]) {
    int tid = threadIdx.x;
    int l = tid & 63, wid = tid >> 6;
    int ar = l & 15, ak = (l >> 4) * 8;
    int mrow = (wid >> 1) * 64, ncol = (wid & 1) * 64;
    int srow = wid * 32 + (l >> 2);
    int scol = (l & 3) * 8;
    const _Float16* ga0 = A + (size_t)(row0 + srow) * DMODEL + scol;
    const _Float16* ga1 = A + (size_t)(row0 + srow + 16) * DMODEL + scol;
    const _Float16* gb0 = B + (size_t)(col0 + srow) * DMODEL + scol;
    const _Float16* gb1 = B + (size_t)(col0 + srow + 16) * DMODEL + scol;
    _Float16* la0 = As + wid * 1024 + l * 8;
    _Float16* la1 = As + wid * 1024 + 512 + l * 8;
    _Float16* lb0 = Bs + wid * 1024 + l * 8;
    _Float16* lb1 = Bs + wid * 1024 + 512 + l * 8;
    for (int k0 = 0; k0 < DMODEL; k0 += 32) {
        GLOAD16(ga0 + k0, la0);
        GLOAD16(ga1 + k0, la1);
        GLOAD16(gb0 + k0, lb0);
        GLOAD16(gb1 + k0, lb1);
        __syncthreads();
        half8 af[4], bf[4];
#pragma unroll
        for (int mi = 0; mi < 4; mi++)
            af[mi] = *(const half8*)(As + (mrow + mi * 16 + ar) * 32 + ak);
#pragma unroll
        for (int ni = 0; ni < 4; ni++)
            bf[ni] = *(const half8*)(Bs + (ncol + ni * 16 + ar) * 32 + ak);
#pragma unroll
        for (int mi = 0; mi < 4; mi++)
#pragma unroll
            for (int ni = 0; ni < 4; ni++)
                acc[mi][ni] = __builtin_amdgcn_mfma_f32_16x16x32_f16(af[mi], bf[ni], acc[mi][ni], 0, 0, 0);
        __syncthreads();
    }
}

// ---------------- fused Q/K/V projection + posbias writer ----------------
__global__ __launch_bounds__(256) void proj3_kernel(const _Float16* __restrict__ Xh,
                                                    const _Float16* __restrict__ Wqh,
                                                    const _Float16* __restrict__ Wkh,
                                                    const _Float16* __restrict__ Wvh,
                                                    _Float16* __restrict__ Qh,
                                                    _Float16* __restrict__ Kh,
                                                    _Float16* __restrict__ Vt,
                                                    const float* __restrict__ lut,
                                                    float* __restrict__ posb) {
    __shared__ _Float16 As[128 * 32];
    __shared__ _Float16 Bs[128 * 32];
    int z = blockIdx.z;
    if (z == 3) {
        int flat = blockIdx.y * 8 + blockIdx.x;
        const size_t total = (size_t)NHEAD * SEQ * SEQ / 4;
        for (size_t idx = (size_t)flat * 256 + threadIdx.x; idx < total; idx += 65536) {
            size_t e = idx * 4;
            int k = (int)(e & 2047);
            int q = (int)((e >> 11) & 2047);
            int h = (int)(e >> 22);
            f32x4 v;
            __builtin_memcpy(&v, lut + h * LUTW + (k - q + 2047), 16);
            nt_store_f4(posb + e, v);
        }
        return;
    }
    const _Float16* B = (z == 0) ? Wqh : (z == 1) ? Wkh : Wvh;
    int row0 = blockIdx.y * 128, col0 = blockIdx.x * 128;
    f32x4 acc[4][4] = {};
    gemm_body_gll(Xh, B, As, Bs, row0, col0, acc);
    int l = threadIdx.x & 63, wid = threadIdx.x >> 6;
    int r0 = row0 + (wid >> 1) * 64;
    int c0 = col0 + (wid & 1) * 64;
    int cr = (l >> 4) * 4, cc = l & 15;
    if (z < 2) {
        _Float16* C = z == 0 ? Qh : Kh;
#pragma unroll
        for (int mi = 0; mi < 4; mi++)
#pragma unroll
            for (int ni = 0; ni < 4; ni++) {
                int c = c0 + ni * 16 + cc;
#pragma unroll
                for (int j = 0; j < 4; j++)
                    C[(size_t)(r0 + mi * 16 + cr + j) * DMODEL + c] = (_Float16)acc[mi][ni][j];
            }
    } else {
#pragma unroll
        for (int mi = 0; mi < 4; mi++)
#pragma unroll
            for (int ni = 0; ni < 4; ni++) {
                int c = c0 + ni * 16 + cc;
                int h = c >> 6, hd = c & 63;
                int r = r0 + mi * 16 + cr;
                int b = r >> 11, s0 = r & 2047;
                half4 pk;
#pragma unroll
                for (int j = 0; j < 4; j++) pk[j] = (_Float16)acc[mi][ni][j];
                *(half4*)(Vt + (size_t)((b * NHEAD + h) * HEADD + hd) * SEQ + s0) = pk;
            }
    }
}

// ---------------- output projection: gload-lds staged, fp32 C ----------------
__global__ __launch_bounds__(256) void outgemm_kernel(const _Float16* __restrict__ A,
                                                      const _Float16* __restrict__ B,
                                                      float* __restrict__ C) {
    __shared__ _Float16 As[128 * 32];
    __shared__ _Float16 Bs[128 * 32];
    int row0 = blockIdx.y * 128, col0 = blockIdx.x * 128;
    f32x4 acc[4][4] = {};
    gemm_body_gll(A, B, As, Bs, row0, col0, acc);
    int l = threadIdx.x & 63, wid = threadIdx.x >> 6;
    int r0 = row0 + (wid >> 1) * 64;
    int c0 = col0 + (wid & 1) * 64;
    int cr = (l >> 4) * 4, cc = l & 15;
#pragma unroll
    for (int mi = 0; mi < 4; mi++)
#pragma unroll
        for (int ni = 0; ni < 4; ni++) {
            int c = c0 + ni * 16 + cc;
#pragma unroll
            for (int j = 0; j < 4; j++)
                C[(size_t)(r0 + mi * 16 + cr + j) * DMODEL + c] = acc[mi][ni][j];
        }
}

// ---------------- fused attention: 8 waves, 4 q-blocks per tile; P1 K_STEP=128 ----------------
__global__ __launch_bounds__(512) void attn_kernel(const _Float16* __restrict__ Q,
                                                   const _Float16* __restrict__ Kg,
                                                   const _Float16* __restrict__ Vg,
                                                   const float* __restrict__ lut,
                                                   const int* __restrict__ mask,
                                                   float* __restrict__ wts,
                                                   _Float16* __restrict__ attn0) {
    __shared__ _Float16 shm[128 * 68];       // P1: K[128][68]; P2: K[64][68] + V[64][68]
    __shared__ _Float16 Pl[8][16][72];
    int tid = threadIdx.x;
    int l = tid & 63, wid = tid >> 6;   // 8 waves
    int wsub = wid & 3, psel = wid >> 2;
    int bid = blockIdx.x;               // 256 blocks
    int xcd = bid & 7, idx = bid >> 3;
    int bh = (idx >> 3) * 8 + xcd;      // XCD-pinned K/V
    int qp = (idx & 7) * 2 + psel;
    int b = bh >> 4, h = bh & 15;
    int qbaseA = qp * 64 + wsub * 16;
    int qbaseB = qbaseA + 1024;
    size_t hoff = (size_t)(b * SEQ) * DMODEL + h * HEADD;
    int ar = l & 15, g = l >> 4, ak = g * 8;
    const float* luth = lut + h * LUTW;
    float* ob = wts + (size_t)bh * SEQ * SEQ;
    int qA = qbaseA + ar;
    int qB = qbaseB + ar;

    half8 qfA[2], qfB[2];
#pragma unroll
    for (int kk = 0; kk < 2; kk++) {
        qfA[kk] = *(const half8*)(Q + hoff + (size_t)qA * DMODEL + kk * 32 + ak);
        qfB[kk] = *(const half8*)(Q + hoff + (size_t)qB * DMODEL + kk * 32 + ak);
    }

    // ---------- P1: stats for A and B, K_STEP = 128 ----------
    // staging: 512 threads, row sr1 = tid>>2 (0..127), col sc1 = (tid&3)*16 (2 half8)
    {
        _Float16 (*Kt)[68] = (_Float16(*)[68])shm;
        int sr1 = tid >> 2, sc1 = (tid & 3) * 16;
        const _Float16* K1src = Kg + hoff + sc1;
        half8 s0 = *(const half8*)(K1src + (size_t)sr1 * DMODEL);
        half8 s1 = *(const half8*)(K1src + (size_t)sr1 * DMODEL + 8);
        float mA = -3e38f, lsumA = 0.f;
        float mB = -3e38f, lsumB = 0.f;
        for (int k0 = 0; k0 < SEQ; k0 += 128) {
            *(half8*)&Kt[sr1][sc1] = s0;
            *(half8*)&Kt[sr1][sc1 + 8] = s1;
            LDS_BAR();
            if (k0 + 128 < SEQ) {
                s0 = *(const half8*)(K1src + (size_t)(k0 + 128 + sr1) * DMODEL);
                s1 = *(const half8*)(K1src + (size_t)(k0 + 128 + sr1) * DMODEL + 8);
            }
            f32x4 accA[8], accB[8];
#pragma unroll
            for (int ni = 0; ni < 8; ni++) {
                accA[ni] = f32x4{0.f, 0.f, 0.f, 0.f};
                accB[ni] = f32x4{0.f, 0.f, 0.f, 0.f};
#pragma unroll
                for (int kk = 0; kk < 2; kk++) {
                    half8 kf = *(const half8*)&Kt[ni * 16 + ar][kk * 32 + ak];
                    accA[ni] = __builtin_amdgcn_mfma_f32_16x16x32_f16(kf, qfA[kk], accA[ni], 0, 0, 0);
                    accB[ni] = __builtin_amdgcn_mfma_f32_16x16x32_f16(kf, qfB[kk], accB[ni], 0, 0, 0);
                }
            }
            LDS_BAR();
            // stats A: two halves of 16 (register cap), exact R8 merge order
            {
                float hm[2], hs[2];
#pragma unroll
                for (int half = 0; half < 2; half++) {
                    float vv[16];
#pragma unroll
                    for (int ni = 0; ni < 4; ni++) {
                        int nn = half * 4 + ni;
                        int kcol = k0 + nn * 16 + g * 4;
                        int4 mk = *(const int4*)(mask + b * SEQ + kcol);
                        const int* mp = (const int*)&mk;
                        f32x4 lb4;
                        __builtin_memcpy(&lb4, luth + kcol - qA + 2047, 16);
#pragma unroll
                        for (int j = 0; j < 4; j++)
                            vv[ni * 4 + j] = mp[j] ? (accA[nn][j] + lb4[j]) : -1e9f;
                    }
                    float t8[8];
#pragma unroll
                    for (int t = 0; t < 8; t++) t8[t] = fmaxf(vv[t], vv[t + 8]);
                    float t4a = fmaxf(t8[0], t8[4]), t4b = fmaxf(t8[1], t8[5]);
                    float t4c = fmaxf(t8[2], t8[6]), t4d = fmaxf(t8[3], t8[7]);
                    float vmax = fmaxf(fmaxf(t4a, t4b), fmaxf(t4c, t4d));
                    float p0 = 0.f, p1 = 0.f, p2 = 0.f, p3 = 0.f;
#pragma unroll
                    for (int t = 0; t < 16; t += 4) {
                        p0 += __expf(vv[t] - vmax);
                        p1 += __expf(vv[t + 1] - vmax);
                        p2 += __expf(vv[t + 2] - vmax);
                        p3 += __expf(vv[t + 3] - vmax);
                    }
                    hm[half] = vmax;
                    hs[half] = (p0 + p1) + (p2 + p3);
                }
                float mn = fmaxf(mA, fmaxf(hm[0], hm[1]));
                lsumA = lsumA * __expf(mA - mn) + hs[0] * __expf(hm[0] - mn) + hs[1] * __expf(hm[1] - mn);
                mA = mn;
            }
            // stats B
            {
                float hm[2], hs[2];
#pragma unroll
                for (int half = 0; half < 2; half++) {
                    float vv[16];
#pragma unroll
                    for (int ni = 0; ni < 4; ni++) {
                        int nn = half * 4 + ni;
                        int kcol = k0 + nn * 16 + g * 4;
                        int4 mk = *(const int4*)(mask + b * SEQ + kcol);
                        const int* mp = (const int*)&mk;
                        f32x4 lb4;
                        __builtin_memcpy(&lb4, luth + kcol - qB + 2047, 16);
#pragma unroll
                        for (int j = 0; j < 4; j++)
                            vv[ni * 4 + j] = mp[j] ? (accB[nn][j] + lb4[j]) : -1e9f;
                    }
                    float t8[8];
#pragma unroll
                    for (int t = 0; t < 8; t++) t8[t] = fmaxf(vv[t], vv[t + 8]);
                    float t4a = fmaxf(t8[0], t8[4]), t4b = fmaxf(t8[1], t8[5]);
                    float t4c = fmaxf(t8[2], t8[6]), t4d = fmaxf(t8[3], t8[7]);
                    float vmax = fmaxf(fmaxf(t4a, t4b), fmaxf(t4c, t4d));
                    float p0 = 0.f, p1 = 0.f, p2 = 0.f, p3 = 0.f;
#pragma unroll
                    for (int t = 0; t < 16; t += 4) {
                        p0 += __expf(vv[t] - vmax);
                        p1 += __expf(vv[t + 1] - vmax);
                        p2 += __expf(vv[t + 2] - vmax);
                        p3 += __expf(vv[t + 3] - vmax);
                    }
                    hm[half] = vmax;
                    hs[half] = (p0 + p1) + (p2 + p3);
                }
                float mn = fmaxf(mB, fmaxf(hm[0], hm[1]));
                lsumB = lsumB * __expf(mB - mn) + hs[0] * __expf(hm[0] - mn) + hs[1] * __expf(hm[1] - mn);
                mB = mn;
            }
        }
#pragma unroll
        for (int off2 = 16; off2 <= 32; off2 <<= 1) {
            float mo = __shfl_xor(mA, off2);
            float lo = __shfl_xor(lsumA, off2);
            float mn = fmaxf(mA, mo);
            lsumA = lsumA * __expf(mA - mn) + lo * __expf(mo - mn);
            mA = mn;
            mo = __shfl_xor(mB, off2);
            lo = __shfl_xor(lsumB, off2);
            mn = fmaxf(mB, mo);
            lsumB = lsumB * __expf(mB - mn) + lo * __expf(mo - mn);
            mB = mn;
        }
        // stash per-thread stats in Pl-free registers via shm? no — keep in regs below
        // fallthrough with mA/lsumA in scope: store to locals outside block scope
        // (handled by assigning to outer variables)
        // outer declarations:
        shm[0] = shm[0];   // no-op
        // write to outer variables via pointer trick not needed; restructure below
        // (we simply continue in this scope)
        float invlA = 1.0f / lsumA;
        float invlB = 1.0f / lsumB;
        LDS_BAR();   // all waves done with P1 K tile

        // ---------- P2: weights + PV for A and B (K_STEP=64, shared tiles) ----------
        _Float16 (*Kt2)[68] = (_Float16(*)[68])shm;
        _Float16 (*Vl)[68] = (_Float16(*)[68])(shm + 64 * 68);
        int sr = tid >> 3, sc = (tid & 7) * 8;
        const _Float16* Ksrc = Kg + hoff + sc;
        const _Float16* Vsrc = Vg + ((size_t)bh * HEADD + sr) * SEQ + sc;
        half8 t0 = *(const half8*)(Ksrc + (size_t)sr * DMODEL);
        half8 v0 = *(const half8*)(Vsrc);
        f32x4 oaccA[4] = {}, oaccB[4] = {};
        for (int k0 = 0; k0 < SEQ; k0 += 64) {
            *(half8*)&Kt2[sr][sc] = t0;
            *(half8*)&Vl[sr][sc] = v0;
            LDS_BAR();
            int4 mk[4];
            f32x4 lbA[4], lbB[4];
#pragma unroll
            for (int ni = 0; ni < 4; ni++) {
                int kcol = k0 + ni * 16 + g * 4;
                mk[ni] = *(const int4*)(mask + b * SEQ + kcol);
                __builtin_memcpy(&lbA[ni], luth + kcol - qA + 2047, 16);
                __builtin_memcpy(&lbB[ni], luth + kcol - qB + 2047, 16);
            }
            if (k0 + 64 < SEQ) {
                t0 = *(const half8*)(Ksrc + (size_t)(k0 + 64 + sr) * DMODEL);
                v0 = *(const half8*)(Vsrc + k0 + 64);
            }
            f32x4 accA[4] = {}, accB[4] = {};
#pragma unroll
            for (int ni = 0; ni < 4; ni++)
#pragma unroll
                for (int kk = 0; kk < 2; kk++) {
                    half8 kf = *(const half8*)&Kt2[ni * 16 + ar][kk * 32 + ak];
                    accA[ni] = __builtin_amdgcn_mfma_f32_16x16x32_f16(kf, qfA[kk], accA[ni], 0, 0, 0);
                    accB[ni] = __builtin_amdgcn_mfma_f32_16x16x32_f16(kf, qfB[kk], accB[ni], 0, 0, 0);
                }
            // A
#pragma unroll
            for (int ni = 0; ni < 4; ni++) {
                int kcol = k0 + ni * 16 + g * 4;
                const int* mp = (const int*)&mk[ni];
                f32x4 wv;
#pragma unroll
                for (int j = 0; j < 4; j++) {
                    float v = mp[j] ? (accA[ni][j] + lbA[ni][j]) : -1e9f;
                    wv[j] = __expf(v - mA) * invlA;
                }
                nt_store_f4(ob + (size_t)qA * SEQ + kcol, wv);
                half4 ph;
#pragma unroll
                for (int j = 0; j < 4; j++) ph[j] = (_Float16)wv[j];
                *(half4*)&Pl[wid][ar][ni * 16 + g * 4] = ph;
            }
#pragma unroll
            for (int kk2 = 0; kk2 < 2; kk2++) {
                half8 pa = *(half8*)&Pl[wid][ar][kk2 * 32 + g * 8];
#pragma unroll
                for (int ni = 0; ni < 4; ni++) {
                    half8 vf = *(const half8*)&Vl[ni * 16 + ar][kk2 * 32 + g * 8];
                    oaccA[ni] = __builtin_amdgcn_mfma_f32_16x16x32_f16(pa, vf, oaccA[ni], 0, 0, 0);
                }
            }
            // B
#pragma unroll
            for (int ni = 0; ni < 4; ni++) {
                int kcol = k0 + ni * 16 + g * 4;
                const int* mp = (const int*)&mk[ni];
                f32x4 wv;
#pragma unroll
                for (int j = 0; j < 4; j++) {
                    float v = mp[j] ? (accB[ni][j] + lbB[ni][j]) : -1e9f;
                    wv[j] = __expf(v - mB) * invlB;
                }
                nt_store_f4(ob + (size_t)qB * SEQ + kcol, wv);
                half4 ph;
#pragma unroll
                for (int j = 0; j < 4; j++) ph[j] = (_Float16)wv[j];
                *(half4*)&Pl[wid][ar][ni * 16 + g * 4] = ph;
            }
#pragma unroll
            for (int kk2 = 0; kk2 < 2; kk2++) {
                half8 pa = *(half8*)&Pl[wid][ar][kk2 * 32 + g * 8];
#pragma unroll
                for (int ni = 0; ni < 4; ni++) {
                    half8 vf = *(const half8*)&Vl[ni * 16 + ar][kk2 * 32 + g * 8];
                    oaccB[ni] = __builtin_amdgcn_mfma_f32_16x16x32_f16(pa, vf, oaccB[ni], 0, 0, 0);
                }
            }
            LDS_BAR();
        }
#pragma unroll
        for (int ni = 0; ni < 4; ni++)
#pragma unroll
            for (int j = 0; j < 4; j++) {
                attn0[(size_t)(b * SEQ + qbaseA + g * 4 + j) * DMODEL + h * HEADD + ni * 16 + ar] =
                    (_Float16)oaccA[ni][j];
                attn0[(size_t)(b * SEQ + qbaseB + g * 4 + j) * DMODEL + h * HEADD + ni * 16 + ar] =
                    (_Float16)oaccB[ni][j];
            }
    }
}

extern "C" void kernel_launch(void* const* d_in, const int* in_sizes, int n_in,
                              void* d_out, int out_size, void* d_ws, size_t ws_size,
                              hipStream_t stream) {
    const float* hs = (const float*)d_in[0];
    const int* mask = (const int*)d_in[1];
    const float* Wq = (const float*)d_in[2];
    const float* Wk = (const float*)d_in[3];
    const float* Wv = (const float*)d_in[4];
    const float* Wo = (const float*)d_in[5];
    const float* rel_bias = (const float*)d_in[6];

    float* out_attn = (float*)d_out;                       // [2,2048,1024]
    float* out_wts = out_attn + (size_t)2 * SEQ * DMODEL;  // [2,16,2048,2048]
    float* out_posb = out_wts + (size_t)NBH * SEQ * SEQ;   // [1,16,2048,2048]

    char* ws = (char*)d_ws;
    size_t off = 0;
    auto carve = [&](size_t bytes) { void* p = ws + off; off += (bytes + 255) & ~(size_t)255; return p; };
    _Float16* Xh  = (_Float16*)carve((size_t)2 * SEQ * DMODEL * 2);
    _Float16* Wqh = (_Float16*)carve((size_t)DMODEL * DMODEL * 2);
    _Float16* Wkh = (_Float16*)carve((size_t)DMODEL * DMODEL * 2);
    _Float16* Wvh = (_Float16*)carve((size_t)DMODEL * DMODEL * 2);
    _Float16* Woh = (_Float16*)carve((size_t)DMODEL * DMODEL * 2);
    _Float16* Qh  = (_Float16*)carve((size_t)2 * SEQ * DMODEL * 2);
    _Float16* Kh  = (_Float16*)carve((size_t)2 * SEQ * DMODEL * 2);
    _Float16* Vt  = (_Float16*)carve((size_t)NBH * HEADD * SEQ * 2);
    _Float16* A0h = (_Float16*)carve((size_t)2 * SEQ * DMODEL * 2);
    float* lut    = (float*)carve((size_t)NHEAD * LUTW * 4);

    // 1. prep: casts + lut
    prep_kernel<<<4352, 256, 0, stream>>>(hs, Wq, Wk, Wv, Wo, rel_bias,
                                          Xh, Wqh, Wkh, Wvh, Woh, lut);

    // 2. Q/K/V projections (gload-lds staged) + posbias stream
    dim3 pg(DMODEL / 128, (2 * SEQ) / 128, 4);
    proj3_kernel<<<pg, 256, 0, stream>>>(Xh, Wqh, Wkh, Wvh, Qh, Kh, Vt, lut, out_posb);

    // 3. fused attention (P1 K128, P2 K64; 256 blocks x 512 thr)
    attn_kernel<<<256, 512, 0, stream>>>(Qh, Kh, Vt, lut, mask, out_wts, A0h);

    // 4. output projection (gload-lds staged)
    dim3 og(DMODEL / 128, (2 * SEQ) / 128);
    outgemm_kernel<<<og, 256, 0, stream>>>(A0h, Woh, out_attn);
}

// Round 24
// 383.676 us; speedup vs baseline: 1.1638x; 1.1638x over previous
//
#include <hip/hip_runtime.h>

typedef __attribute__((ext_vector_type(8))) _Float16 half8;
typedef __attribute__((ext_vector_type(4))) _Float16 half4;
typedef __attribute__((ext_vector_type(4))) float f32x4;

#define SEQ 2048
#define DMODEL 1024
#define NHEAD 16
#define HEADD 64
#define NBH 32          // B * NHEAD
#define LUTW 4096

__device__ __forceinline__ void nt_store_f4(float* p, f32x4 v) {
    __builtin_nontemporal_store(v, (f32x4*)p);
}

// async global->LDS, 16B per lane (dest = wave-uniform base + lane*16)
#define GLOAD16(gp, lp) __builtin_amdgcn_global_load_lds(                    \
    (const __attribute__((address_space(1))) void*)(gp),                     \
    (__attribute__((address_space(3))) void*)(lp), 16, 0, 0)

// raw barrier: orders LDS only; global loads/stores stay in flight across it
#define LDS_BAR() do {                                   \
    __builtin_amdgcn_sched_barrier(0);                   \
    asm volatile("s_waitcnt lgkmcnt(0)" ::: "memory");   \
    __builtin_amdgcn_sched_barrier(0);                   \
    __builtin_amdgcn_s_barrier();                        \
    __builtin_amdgcn_sched_barrier(0);                   \
} while (0)

// ---------------- T5 relative position bucket ----------------
__device__ __forceinline__ int rel_bucket(int rel) {
    int ret = (rel > 0) ? 16 : 0;
    int rp = rel < 0 ? -rel : rel;
    if (rp < 8) return ret + rp;
    float x = logf((float)rp * 0.125f) / 2.7725887f * 8.0f;
    int v = 8 + (int)x;
    v = v < 15 ? v : 15;
    return ret + v;
}

// ---------------- prep: all casts + bias LUT in one launch ----------------
__global__ __launch_bounds__(256) void prep_kernel(const float* __restrict__ hs,
                                                   const float* __restrict__ Wq,
                                                   const float* __restrict__ Wk,
                                                   const float* __restrict__ Wv,
                                                   const float* __restrict__ Wo,
                                                   const float* __restrict__ rel_bias,
                                                   _Float16* __restrict__ Xh,
                                                   _Float16* __restrict__ Wqh,
                                                   _Float16* __restrict__ Wkh,
                                                   _Float16* __restrict__ Wvh,
                                                   _Float16* __restrict__ Woh,
                                                   float* __restrict__ lut) {
    int bid = blockIdx.x;
    if (bid < 4096) {
        const float* in;
        _Float16* out;
        int base;
        if (bid < 2048)      { in = hs; out = Xh;  base = bid; }
        else if (bid < 2560) { in = Wq; out = Wqh; base = bid - 2048; }
        else if (bid < 3072) { in = Wk; out = Wkh; base = bid - 2560; }
        else if (bid < 3584) { in = Wv; out = Wvh; base = bid - 3072; }
        else                 { in = Wo; out = Woh; base = bid - 3584; }
        int i = (base * 256 + threadIdx.x) * 8;
        f32x4 a = *(const f32x4*)(in + i);
        f32x4 b = *(const f32x4*)(in + i + 4);
        half8 r;
        r[0] = (_Float16)a[0]; r[1] = (_Float16)a[1];
        r[2] = (_Float16)a[2]; r[3] = (_Float16)a[3];
        r[4] = (_Float16)b[0]; r[5] = (_Float16)b[1];
        r[6] = (_Float16)b[2]; r[7] = (_Float16)b[3];
        *(half8*)(out + i) = r;
    } else {
        int i = (bid - 4096) * 256 + threadIdx.x;   // 16 * 4096
        int h = i >> 12;
        int idx = i & (LUTW - 1);
        int rel = idx - 2047;
        int b = rel_bucket(rel);
        lut[i] = rel_bias[b * NHEAD + h];
    }
}

// ---------------- m97-style GEMM body: global_load_lds staging, 128x128 tile ----------------
__device__ __forceinline__ void gemm_body_gll(const _Float16* __restrict__ A,
                                              const _Float16* __restrict__ B,
                                              _Float16* As, _Float16* Bs,
                                              int row0, int col0,
                                              f32x4 (&acc)[4][4]) {
    int tid = threadIdx.x;
    int l = tid & 63, wid = tid >> 6;
    int ar = l & 15, ak = (l >> 4) * 8;
    int mrow = (wid >> 1) * 64, ncol = (wid & 1) * 64;
    int srow = wid * 32 + (l >> 2);
    int scol = (l & 3) * 8;
    const _Float16* ga0 = A + (size_t)(row0 + srow) * DMODEL + scol;
    const _Float16* ga1 = A + (size_t)(row0 + srow + 16) * DMODEL + scol;
    const _Float16* gb0 = B + (size_t)(col0 + srow) * DMODEL + scol;
    const _Float16* gb1 = B + (size_t)(col0 + srow + 16) * DMODEL + scol;
    _Float16* la0 = As + wid * 1024 + l * 8;
    _Float16* la1 = As + wid * 1024 + 512 + l * 8;
    _Float16* lb0 = Bs + wid * 1024 + l * 8;
    _Float16* lb1 = Bs + wid * 1024 + 512 + l * 8;
    for (int k0 = 0; k0 < DMODEL; k0 += 32) {
        GLOAD16(ga0 + k0, la0);
        GLOAD16(ga1 + k0, la1);
        GLOAD16(gb0 + k0, lb0);
        GLOAD16(gb1 + k0, lb1);
        __syncthreads();
        half8 af[4], bf[4];
#pragma unroll
        for (int mi = 0; mi < 4; mi++)
            af[mi] = *(const half8*)(As + (mrow + mi * 16 + ar) * 32 + ak);
#pragma unroll
        for (int ni = 0; ni < 4; ni++)
            bf[ni] = *(const half8*)(Bs + (ncol + ni * 16 + ar) * 32 + ak);
#pragma unroll
        for (int mi = 0; mi < 4; mi++)
#pragma unroll
            for (int ni = 0; ni < 4; ni++)
                acc[mi][ni] = __builtin_amdgcn_mfma_f32_16x16x32_f16(af[mi], bf[ni], acc[mi][ni], 0, 0, 0);
        __syncthreads();
    }
}

// ---------------- fused Q/K/V projection + posbias writer ----------------
// z = 0(Q) 1(K) 2(V->Vt) 3(posbias stream, overlaps GEMM compute)
__global__ __launch_bounds__(256) void proj3_kernel(const _Float16* __restrict__ Xh,
                                                    const _Float16* __restrict__ Wqh,
                                                    const _Float16* __restrict__ Wkh,
                                                    const _Float16* __restrict__ Wvh,
                                                    _Float16* __restrict__ Qh,
                                                    _Float16* __restrict__ Kh,
                                                    _Float16* __restrict__ Vt,
                                                    const float* __restrict__ lut,
                                                    float* __restrict__ posb) {
    __shared__ _Float16 As[128 * 32];
    __shared__ _Float16 Bs[128 * 32];
    int z = blockIdx.z;
    if (z == 3) {
        int flat = blockIdx.y * 8 + blockIdx.x;        // 0..255
        const size_t total = (size_t)NHEAD * SEQ * SEQ / 4;   // 16,777,216 float4
        for (size_t idx = (size_t)flat * 256 + threadIdx.x; idx < total; idx += 65536) {
            size_t e = idx * 4;
            int k = (int)(e & 2047);
            int q = (int)((e >> 11) & 2047);
            int h = (int)(e >> 22);
            f32x4 v;
            __builtin_memcpy(&v, lut + h * LUTW + (k - q + 2047), 16);
            nt_store_f4(posb + e, v);
        }
        return;
    }
    const _Float16* B = (z == 0) ? Wqh : (z == 1) ? Wkh : Wvh;
    int row0 = blockIdx.y * 128, col0 = blockIdx.x * 128;
    f32x4 acc[4][4] = {};
    gemm_body_gll(Xh, B, As, Bs, row0, col0, acc);
    int l = threadIdx.x & 63, wid = threadIdx.x >> 6;
    int r0 = row0 + (wid >> 1) * 64;
    int c0 = col0 + (wid & 1) * 64;
    int cr = (l >> 4) * 4, cc = l & 15;
    if (z < 2) {
        _Float16* C = z == 0 ? Qh : Kh;
#pragma unroll
        for (int mi = 0; mi < 4; mi++)
#pragma unroll
            for (int ni = 0; ni < 4; ni++) {
                int c = c0 + ni * 16 + cc;
#pragma unroll
                for (int j = 0; j < 4; j++)
                    C[(size_t)(r0 + mi * 16 + cr + j) * DMODEL + c] = (_Float16)acc[mi][ni][j];
            }
    } else {
#pragma unroll
        for (int mi = 0; mi < 4; mi++)
#pragma unroll
            for (int ni = 0; ni < 4; ni++) {
                int c = c0 + ni * 16 + cc;
                int h = c >> 6, hd = c & 63;
                int r = r0 + mi * 16 + cr;
                int b = r >> 11, s0 = r & 2047;
                half4 pk;
#pragma unroll
                for (int j = 0; j < 4; j++) pk[j] = (_Float16)acc[mi][ni][j];
                *(half4*)(Vt + (size_t)((b * NHEAD + h) * HEADD + hd) * SEQ + s0) = pk;
            }
    }
}

// ---------------- output projection: gload-lds staged, fp32 C ----------------
__global__ __launch_bounds__(256) void outgemm_kernel(const _Float16* __restrict__ A,
                                                      const _Float16* __restrict__ B,
                                                      float* __restrict__ C) {
    __shared__ _Float16 As[128 * 32];
    __shared__ _Float16 Bs[128 * 32];
    int row0 = blockIdx.y * 128, col0 = blockIdx.x * 128;
    f32x4 acc[4][4] = {};
    gemm_body_gll(A, B, As, Bs, row0, col0, acc);
    int l = threadIdx.x & 63, wid = threadIdx.x >> 6;
    int r0 = row0 + (wid >> 1) * 64;
    int c0 = col0 + (wid & 1) * 64;
    int cr = (l >> 4) * 4, cc = l & 15;
#pragma unroll
    for (int mi = 0; mi < 4; mi++)
#pragma unroll
        for (int ni = 0; ni < 4; ni++) {
            int c = c0 + ni * 16 + cc;
#pragma unroll
            for (int j = 0; j < 4; j++)
                C[(size_t)(r0 + mi * 16 + cr + j) * DMODEL + c] = acc[mi][ni][j];
        }
}

// ---------------- fused attention: 8 waves, 4 q-blocks share each staged tile ----------------
__global__ __launch_bounds__(512) void attn_kernel(const _Float16* __restrict__ Q,
                                                   const _Float16* __restrict__ Kg,
                                                   const _Float16* __restrict__ Vg,
                                                   const float* __restrict__ lut,
                                                   const int* __restrict__ mask,
                                                   float* __restrict__ wts,
                                                   _Float16* __restrict__ attn0) {
    __shared__ _Float16 Kt[64][68];
    __shared__ _Float16 Vl[64][68];
    __shared__ _Float16 Pl[8][16][72];
    int tid = threadIdx.x;
    int l = tid & 63, wid = tid >> 6;   // 8 waves
    int wsub = wid & 3, psel = wid >> 2;
    int bid = blockIdx.x;               // 256 blocks
    int xcd = bid & 7, idx = bid >> 3;  // idx 0..31
    int bh = (idx >> 3) * 8 + xcd;      // XCD-pinned K/V
    int qp = (idx & 7) * 2 + psel;      // pair 0..15
    int b = bh >> 4, h = bh & 15;
    int qbaseA = qp * 64 + wsub * 16;   // rows 0..1023
    int qbaseB = qbaseA + 1024;         // rows 1024..2047
    size_t hoff = (size_t)(b * SEQ) * DMODEL + h * HEADD;
    int ar = l & 15, g = l >> 4, ak = g * 8;
    const float* luth = lut + h * LUTW;
    float* ob = wts + (size_t)bh * SEQ * SEQ;
    int qA = qbaseA + ar;
    int qB = qbaseB + ar;

    int sr = tid >> 3, sc = (tid & 7) * 8;   // 512 threads stage 64x64 tile
    const _Float16* Ksrc = Kg + hoff + sc;
    const _Float16* Vsrc = Vg + ((size_t)bh * HEADD + sr) * SEQ + sc;

    half8 qfA[2], qfB[2];
#pragma unroll
    for (int kk = 0; kk < 2; kk++) {
        qfA[kk] = *(const half8*)(Q + hoff + (size_t)qA * DMODEL + kk * 32 + ak);
        qfB[kk] = *(const half8*)(Q + hoff + (size_t)qB * DMODEL + kk * 32 + ak);
    }

    // ---------- P1: online stats for A and B (shared K tiles, 4-way) ----------
    half8 s0 = *(const half8*)(Ksrc + (size_t)sr * DMODEL);
    float mA = -3e38f, lsumA = 0.f;
    float mB = -3e38f, lsumB = 0.f;
    for (int k0 = 0; k0 < SEQ; k0 += 64) {
        *(half8*)&Kt[sr][sc] = s0;
        LDS_BAR();
        int4 mk[4];
        f32x4 lbA[4], lbB[4];
#pragma unroll
        for (int ni = 0; ni < 4; ni++) {
            int kcol = k0 + ni * 16 + g * 4;
            mk[ni] = *(const int4*)(mask + b * SEQ + kcol);
            __builtin_memcpy(&lbA[ni], luth + kcol - qA + 2047, 16);
            __builtin_memcpy(&lbB[ni], luth + kcol - qB + 2047, 16);
        }
        if (k0 + 64 < SEQ)
            s0 = *(const half8*)(Ksrc + (size_t)(k0 + 64 + sr) * DMODEL);
        f32x4 accA[4] = {}, accB[4] = {};
#pragma unroll
        for (int ni = 0; ni < 4; ni++)
#pragma unroll
            for (int kk = 0; kk < 2; kk++) {
                half8 kf = *(const half8*)&Kt[ni * 16 + ar][kk * 32 + ak];
                accA[ni] = __builtin_amdgcn_mfma_f32_16x16x32_f16(kf, qfA[kk], accA[ni], 0, 0, 0);
                accB[ni] = __builtin_amdgcn_mfma_f32_16x16x32_f16(kf, qfB[kk], accB[ni], 0, 0, 0);
            }
        LDS_BAR();
        // --- stats A ---
        {
            float vv[16];
#pragma unroll
            for (int ni = 0; ni < 4; ni++) {
                const int* mp = (const int*)&mk[ni];
#pragma unroll
                for (int j = 0; j < 4; j++)
                    vv[ni * 4 + j] = mp[j] ? (accA[ni][j] + lbA[ni][j]) : -1e9f;
            }
            float t8[8];
#pragma unroll
            for (int t = 0; t < 8; t++) t8[t] = fmaxf(vv[t], vv[t + 8]);
            float t4a = fmaxf(t8[0], t8[4]), t4b = fmaxf(t8[1], t8[5]);
            float t4c = fmaxf(t8[2], t8[6]), t4d = fmaxf(t8[3], t8[7]);
            float vmax = fmaxf(fmaxf(t4a, t4b), fmaxf(t4c, t4d));
            float mn = fmaxf(mA, vmax);
            float scale = __expf(mA - mn);
            float e[16];
#pragma unroll
            for (int t = 0; t < 16; t++) e[t] = __expf(vv[t] - mn);
            float s8[8];
#pragma unroll
            for (int t = 0; t < 8; t++) s8[t] = e[t] + e[t + 8];
            float s4a = s8[0] + s8[4], s4b = s8[1] + s8[5];
            float s4c = s8[2] + s8[6], s4d = s8[3] + s8[7];
            lsumA = lsumA * scale + (s4a + s4b) + (s4c + s4d);
            mA = mn;
        }
        // --- stats B ---
        {
            float vv[16];
#pragma unroll
            for (int ni = 0; ni < 4; ni++) {
                const int* mp = (const int*)&mk[ni];
#pragma unroll
                for (int j = 0; j < 4; j++)
                    vv[ni * 4 + j] = mp[j] ? (accB[ni][j] + lbB[ni][j]) : -1e9f;
            }
            float t8[8];
#pragma unroll
            for (int t = 0; t < 8; t++) t8[t] = fmaxf(vv[t], vv[t + 8]);
            float t4a = fmaxf(t8[0], t8[4]), t4b = fmaxf(t8[1], t8[5]);
            float t4c = fmaxf(t8[2], t8[6]), t4d = fmaxf(t8[3], t8[7]);
            float vmax = fmaxf(fmaxf(t4a, t4b), fmaxf(t4c, t4d));
            float mn = fmaxf(mB, vmax);
            float scale = __expf(mB - mn);
            float e[16];
#pragma unroll
            for (int t = 0; t < 16; t++) e[t] = __expf(vv[t] - mn);
            float s8[8];
#pragma unroll
            for (int t = 0; t < 8; t++) s8[t] = e[t] + e[t + 8];
            float s4a = s8[0] + s8[4], s4b = s8[1] + s8[5];
            float s4c = s8[2] + s8[6], s4d = s8[3] + s8[7];
            lsumB = lsumB * scale + (s4a + s4b) + (s4c + s4d);
            mB = mn;
        }
    }
    // prefetch P2 tile 0 (K and V) before the cross-lane reductions
    half8 t0 = *(const half8*)(Ksrc + (size_t)sr * DMODEL);
    half8 v0 = *(const half8*)(Vsrc);
#pragma unroll
    for (int off2 = 16; off2 <= 32; off2 <<= 1) {
        float mo = __shfl_xor(mA, off2);
        float lo = __shfl_xor(lsumA, off2);
        float mn = fmaxf(mA, mo);
        lsumA = lsumA * __expf(mA - mn) + lo * __expf(mo - mn);
        mA = mn;
        mo = __shfl_xor(mB, off2);
        lo = __shfl_xor(lsumB, off2);
        mn = fmaxf(mB, mo);
        lsumB = lsumB * __expf(mB - mn) + lo * __expf(mo - mn);
        mB = mn;
    }
    float invlA = 1.0f / lsumA;
    float invlB = 1.0f / lsumB;
    LDS_BAR();   // all waves done with P1 Kt

    // ---------- P2: weights + PV for A and B (shared K+V tiles, 4-way) ----------
    f32x4 oaccA[4] = {}, oaccB[4] = {};
    for (int k0 = 0; k0 < SEQ; k0 += 64) {
        *(half8*)&Kt[sr][sc] = t0;
        *(half8*)&Vl[sr][sc] = v0;
        LDS_BAR();
        int4 mk[4];
        f32x4 lbA[4], lbB[4];
#pragma unroll
        for (int ni = 0; ni < 4; ni++) {
            int kcol = k0 + ni * 16 + g * 4;
            mk[ni] = *(const int4*)(mask + b * SEQ + kcol);
            __builtin_memcpy(&lbA[ni], luth + kcol - qA + 2047, 16);
            __builtin_memcpy(&lbB[ni], luth + kcol - qB + 2047, 16);
        }
        if (k0 + 64 < SEQ) {
            t0 = *(const half8*)(Ksrc + (size_t)(k0 + 64 + sr) * DMODEL);
            v0 = *(const half8*)(Vsrc + k0 + 64);
        }
        f32x4 accA[4] = {}, accB[4] = {};
#pragma unroll
        for (int ni = 0; ni < 4; ni++)
#pragma unroll
            for (int kk = 0; kk < 2; kk++) {
                half8 kf = *(const half8*)&Kt[ni * 16 + ar][kk * 32 + ak];
                accA[ni] = __builtin_amdgcn_mfma_f32_16x16x32_f16(kf, qfA[kk], accA[ni], 0, 0, 0);
                accB[ni] = __builtin_amdgcn_mfma_f32_16x16x32_f16(kf, qfB[kk], accB[ni], 0, 0, 0);
            }
        // --- A: weights + Pl + PV ---
#pragma unroll
        for (int ni = 0; ni < 4; ni++) {
            int kcol = k0 + ni * 16 + g * 4;
            const int* mp = (const int*)&mk[ni];
            f32x4 wv;
#pragma unroll
            for (int j = 0; j < 4; j++) {
                float v = mp[j] ? (accA[ni][j] + lbA[ni][j]) : -1e9f;
                wv[j] = __expf(v - mA) * invlA;
            }
            nt_store_f4(ob + (size_t)qA * SEQ + kcol, wv);
            half4 ph;
#pragma unroll
            for (int j = 0; j < 4; j++) ph[j] = (_Float16)wv[j];
            *(half4*)&Pl[wid][ar][ni * 16 + g * 4] = ph;
        }
#pragma unroll
        for (int kk2 = 0; kk2 < 2; kk2++) {
            half8 pa = *(half8*)&Pl[wid][ar][kk2 * 32 + g * 8];
#pragma unroll
            for (int ni = 0; ni < 4; ni++) {
                half8 vf = *(const half8*)&Vl[ni * 16 + ar][kk2 * 32 + g * 8];
                oaccA[ni] = __builtin_amdgcn_mfma_f32_16x16x32_f16(pa, vf, oaccA[ni], 0, 0, 0);
            }
        }
        // --- B: weights + Pl + PV ---
#pragma unroll
        for (int ni = 0; ni < 4; ni++) {
            int kcol = k0 + ni * 16 + g * 4;
            const int* mp = (const int*)&mk[ni];
            f32x4 wv;
#pragma unroll
            for (int j = 0; j < 4; j++) {
                float v = mp[j] ? (accB[ni][j] + lbB[ni][j]) : -1e9f;
                wv[j] = __expf(v - mB) * invlB;
            }
            nt_store_f4(ob + (size_t)qB * SEQ + kcol, wv);
            half4 ph;
#pragma unroll
            for (int j = 0; j < 4; j++) ph[j] = (_Float16)wv[j];
            *(half4*)&Pl[wid][ar][ni * 16 + g * 4] = ph;
        }
#pragma unroll
        for (int kk2 = 0; kk2 < 2; kk2++) {
            half8 pa = *(half8*)&Pl[wid][ar][kk2 * 32 + g * 8];
#pragma unroll
            for (int ni = 0; ni < 4; ni++) {
                half8 vf = *(const half8*)&Vl[ni * 16 + ar][kk2 * 32 + g * 8];
                oaccB[ni] = __builtin_amdgcn_mfma_f32_16x16x32_f16(pa, vf, oaccB[ni], 0, 0, 0);
            }
        }
        LDS_BAR();
    }
#pragma unroll
    for (int ni = 0; ni < 4; ni++)
#pragma unroll
        for (int j = 0; j < 4; j++) {
            attn0[(size_t)(b * SEQ + qbaseA + g * 4 + j) * DMODEL + h * HEADD + ni * 16 + ar] =
                (_Float16)oaccA[ni][j];
            attn0[(size_t)(b * SEQ + qbaseB + g * 4 + j) * DMODEL + h * HEADD + ni * 16 + ar] =
                (_Float16)oaccB[ni][j];
        }
}

extern "C" void kernel_launch(void* const* d_in, const int* in_sizes, int n_in,
                              void* d_out, int out_size, void* d_ws, size_t ws_size,
                              hipStream_t stream) {
    const float* hs = (const float*)d_in[0];
    const int* mask = (const int*)d_in[1];
    const float* Wq = (const float*)d_in[2];
    const float* Wk = (const float*)d_in[3];
    const float* Wv = (const float*)d_in[4];
    const float* Wo = (const float*)d_in[5];
    const float* rel_bias = (const float*)d_in[6];

    float* out_attn = (float*)d_out;                       // [2,2048,1024]
    float* out_wts = out_attn + (size_t)2 * SEQ * DMODEL;  // [2,16,2048,2048]
    float* out_posb = out_wts + (size_t)NBH * SEQ * SEQ;   // [1,16,2048,2048]

    char* ws = (char*)d_ws;
    size_t off = 0;
    auto carve = [&](size_t bytes) { void* p = ws + off; off += (bytes + 255) & ~(size_t)255; return p; };
    _Float16* Xh  = (_Float16*)carve((size_t)2 * SEQ * DMODEL * 2);
    _Float16* Wqh = (_Float16*)carve((size_t)DMODEL * DMODEL * 2);
    _Float16* Wkh = (_Float16*)carve((size_t)DMODEL * DMODEL * 2);
    _Float16* Wvh = (_Float16*)carve((size_t)DMODEL * DMODEL * 2);
    _Float16* Woh = (_Float16*)carve((size_t)DMODEL * DMODEL * 2);
    _Float16* Qh  = (_Float16*)carve((size_t)2 * SEQ * DMODEL * 2);
    _Float16* Kh  = (_Float16*)carve((size_t)2 * SEQ * DMODEL * 2);
    _Float16* Vt  = (_Float16*)carve((size_t)NBH * HEADD * SEQ * 2);
    _Float16* A0h = (_Float16*)carve((size_t)2 * SEQ * DMODEL * 2);
    float* lut    = (float*)carve((size_t)NHEAD * LUTW * 4);

    // 1. prep: casts + lut
    prep_kernel<<<4352, 256, 0, stream>>>(hs, Wq, Wk, Wv, Wo, rel_bias,
                                          Xh, Wqh, Wkh, Wvh, Woh, lut);

    // 2. Q/K/V projections (gload-lds staged) + posbias stream
    dim3 pg(DMODEL / 128, (2 * SEQ) / 128, 4);
    proj3_kernel<<<pg, 256, 0, stream>>>(Xh, Wqh, Wkh, Wvh, Qh, Kh, Vt, lut, out_posb);

    // 3. fused attention (8 waves, 4 q-blocks per staged tile, 256 blocks)
    attn_kernel<<<256, 512, 0, stream>>>(Qh, Kh, Vt, lut, mask, out_wts, A0h);

    // 4. output projection (gload-lds staged)
    dim3 og(DMODEL / 128, (2 * SEQ) / 128);
    outgemm_kernel<<<og, 256, 0, stream>>>(A0h, Woh, out_attn);
}